// Round 3
// baseline (788.989 us; speedup 1.0000x reference)
//
#include <hip/hip_runtime.h>

#define NFEAT 128
#define NHID 64
#define NCLASS 40

// ---------------- bf16 helpers (storage-only precision; compute is fp32) ----------------

__device__ __forceinline__ float bfu(unsigned short u) {
    return __uint_as_float((unsigned)u << 16);
}
__device__ __forceinline__ unsigned short fbf(float f) {
    unsigned u = __float_as_uint(f);
    u += 0x7fffu + ((u >> 16) & 1u);        // round-to-nearest-even
    return (unsigned short)(u >> 16);
}

// ======================= degree / normalization =======================

__global__ void deg_kernel(const int* __restrict__ dst, int* __restrict__ deg, int E) {
    int i = blockIdx.x * blockDim.x + threadIdx.x;
    if (i < E) atomicAdd(&deg[dst[i]], 1);
}

__global__ void dinv_kernel(const int* __restrict__ deg, float* __restrict__ dinv, int N) {
    int i = blockIdx.x * blockDim.x + threadIdx.x;
    if (i < N) dinv[i] = rsqrtf((float)deg[i] + 1.0f);  // +1 self loop
}

// ======================= exclusive scan (CSR row_ptr) =======================

__global__ void scan_block_sums(const int* __restrict__ deg, int* __restrict__ bsums, int N) {
    __shared__ int sd[256];
    int t = threadIdx.x;
    int base = blockIdx.x * 1024 + t * 4;
    int s = 0;
    #pragma unroll
    for (int i = 0; i < 4; ++i) { int idx = base + i; if (idx < N) s += deg[idx]; }
    sd[t] = s; __syncthreads();
    for (int off = 128; off > 0; off >>= 1) {
        if (t < off) sd[t] += sd[t + off];
        __syncthreads();
    }
    if (t == 0) bsums[blockIdx.x] = sd[0];
}

__global__ void scan_bsums(int* __restrict__ bsums, int nb, int* __restrict__ row_ptr,
                           int N, int E) {
    __shared__ int sd[256];
    int t = threadIdx.x;
    sd[t] = (t < nb) ? bsums[t] : 0;
    __syncthreads();
    for (int off = 1; off < 256; off <<= 1) {
        int v = (t >= off) ? sd[t - off] : 0;
        __syncthreads();
        sd[t] += v;
        __syncthreads();
    }
    if (t < nb) bsums[t] = (t == 0) ? 0 : sd[t - 1];   // exclusive
    if (t == 0) row_ptr[N] = E;
}

__global__ void scan_final(const int* __restrict__ deg, const int* __restrict__ bsums,
                           int* __restrict__ row_ptr, int N) {
    __shared__ int sd[256];
    int t = threadIdx.x;
    int base = blockIdx.x * 1024 + t * 4;
    int local[4];
    int s = 0;
    #pragma unroll
    for (int i = 0; i < 4; ++i) {
        local[i] = s;
        int idx = base + i;
        s += (idx < N) ? deg[idx] : 0;
    }
    sd[t] = s; __syncthreads();
    for (int off = 1; off < 256; off <<= 1) {
        int v = (t >= off) ? sd[t - off] : 0;
        __syncthreads();
        sd[t] += v;
        __syncthreads();
    }
    int toff = (t == 0) ? 0 : sd[t - 1];
    int boff = bsums[blockIdx.x];
    #pragma unroll
    for (int i = 0; i < 4; ++i) {
        int idx = base + i;
        if (idx < N) row_ptr[idx] = boff + toff + local[i];
    }
}

// ======================= two-level CSR scatter =======================
// Bucket b = 128 consecutive dst nodes; bucket region in csr/ebuf is
// [row_ptr[b*128], row_ptr[(b+1)*128]) -- bases come free from row_ptr.

__global__ void bcur_init(const int* __restrict__ row_ptr, int* __restrict__ bcur, int NB) {
    int b = blockIdx.x * blockDim.x + threadIdx.x;
    if (b < NB) bcur[b] = row_ptr[b << 7];
}

// Pass A: partition (dst,src) pairs into bucket regions. Writes to a bucket are
// temporally clustered (global cursor) -> lines fill fast, stay in L2.
__global__ void bucket_scatter(const int* __restrict__ src, const int* __restrict__ dst,
                               int* __restrict__ bcur, int2* __restrict__ ebuf, int E) {
    int i = blockIdx.x * blockDim.x + threadIdx.x;
    if (i < E) {
        int d = dst[i];
        int pos = atomicAdd(&bcur[d >> 7], 1);
        ebuf[pos] = make_int2(d, src[i]);
    }
}

// Pass B: one workgroup per bucket; LDS per-node cursors; writes confined to
// the bucket's ~8KB csr_src region (single workgroup -> single XCD L2, full lines).
__launch_bounds__(256)
__global__ void bucket_to_csr(const int2* __restrict__ ebuf, const int* __restrict__ row_ptr,
                              int* __restrict__ csr_src, int N) {
    __shared__ int lcur[128];
    __shared__ int se0, se1;
    const int b = blockIdx.x;
    const int n0 = b << 7;
    const int t = threadIdx.x;
    if (t < 128) { int n = n0 + t; if (n < N) lcur[t] = row_ptr[n]; }
    if (t == 0) { se0 = row_ptr[n0]; se1 = row_ptr[min(n0 + 128, N)]; }
    __syncthreads();
    for (int idx = se0 + t; idx < se1; idx += 256) {
        int2 p = ebuf[idx];
        int pos = atomicAdd(&lcur[p.x - n0], 1);
        csr_src[pos] = p.y;
    }
}

// ======================= dense linear =======================
// out[n,:] = bf16( dinv[n] * (f(in[n,:]) @ W) ), f = relu(x + bias_prev) if RELU_BIAS.
// fp32 compute; W + x tile staged in LDS; 4 nodes/thread register blocking.

template<int K, int F, bool RELU_BIAS, bool IN_BF16>
__launch_bounds__(256)
__global__ void lin_kernel(const void* __restrict__ in_, const float* __restrict__ W,
                           const float* __restrict__ bias, const float* __restrict__ dinv,
                           unsigned short* __restrict__ out, int N) {
    constexpr int FT = F / 4;            // feature-quads per node
    constexpr int TG = 256 / FT;         // node groups
    constexpr int NPT = 4;
    constexpr int NODES = TG * NPT;
    constexpr int KP = K + 4;            // pad keeps 16B align, breaks pow2 strides

    __shared__ alignas(16) float Ws[K * F];
    __shared__ alignas(16) float xs[NODES * KP];

    const int tid = threadIdx.x;
    const int n0 = blockIdx.x * NODES;

    for (int q = tid; q < K * F / 4; q += 256)
        ((float4*)Ws)[q] = ((const float4*)W)[q];

    if constexpr (IN_BF16) {
        const unsigned short* in = (const unsigned short*)in_;
        for (int q = tid; q < NODES * (K / 8); q += 256) {
            int ni = q / (K / 8);
            int c = q - ni * (K / 8);
            int n = n0 + ni;
            float v[8];
            if (n < N) {
                uint4 raw = *(const uint4*)(in + (size_t)n * K + c * 8);
                unsigned rr[4] = {raw.x, raw.y, raw.z, raw.w};
                #pragma unroll
                for (int j = 0; j < 4; ++j) {
                    v[2 * j]     = __uint_as_float(rr[j] << 16);
                    v[2 * j + 1] = __uint_as_float(rr[j] & 0xffff0000u);
                }
            } else {
                #pragma unroll
                for (int j = 0; j < 8; ++j) v[j] = 0.f;
            }
            if constexpr (RELU_BIAS) {
                #pragma unroll
                for (int j = 0; j < 8; ++j) v[j] = fmaxf(v[j] + bias[c * 8 + j], 0.f);
            }
            *(float4*)&xs[ni * KP + c * 8]     = make_float4(v[0], v[1], v[2], v[3]);
            *(float4*)&xs[ni * KP + c * 8 + 4] = make_float4(v[4], v[5], v[6], v[7]);
        }
    } else {
        const float* in = (const float*)in_;
        for (int q = tid; q < NODES * (K / 4); q += 256) {
            int ni = q / (K / 4);
            int kq = q - ni * (K / 4);
            int n = n0 + ni;
            float4 v = make_float4(0.f, 0.f, 0.f, 0.f);
            if (n < N) v = ((const float4*)in)[(size_t)n * (K / 4) + kq];
            if constexpr (RELU_BIAS) {
                float4 b = ((const float4*)bias)[kq];
                v.x = fmaxf(v.x + b.x, 0.f);
                v.y = fmaxf(v.y + b.y, 0.f);
                v.z = fmaxf(v.z + b.z, 0.f);
                v.w = fmaxf(v.w + b.w, 0.f);
            }
            *(float4*)&xs[ni * KP + kq * 4] = v;
        }
    }
    __syncthreads();

    const int tx = tid % FT;
    const int tg = tid / FT;
    if (tg >= TG) return;

    float4 acc[NPT];
    #pragma unroll
    for (int i = 0; i < NPT; ++i) acc[i] = make_float4(0.f, 0.f, 0.f, 0.f);

    #pragma unroll 4
    for (int kq = 0; kq < K / 4; ++kq) {
        float4 w0 = *(const float4*)&Ws[(kq * 4 + 0) * F + tx * 4];
        float4 w1 = *(const float4*)&Ws[(kq * 4 + 1) * F + tx * 4];
        float4 w2 = *(const float4*)&Ws[(kq * 4 + 2) * F + tx * 4];
        float4 w3 = *(const float4*)&Ws[(kq * 4 + 3) * F + tx * 4];
        #pragma unroll
        for (int i = 0; i < NPT; ++i) {
            float4 xv = *(const float4*)&xs[(tg * NPT + i) * KP + kq * 4];
            acc[i].x += xv.x * w0.x + xv.y * w1.x + xv.z * w2.x + xv.w * w3.x;
            acc[i].y += xv.x * w0.y + xv.y * w1.y + xv.z * w2.y + xv.w * w3.y;
            acc[i].z += xv.x * w0.z + xv.y * w1.z + xv.z * w2.z + xv.w * w3.z;
            acc[i].w += xv.x * w0.w + xv.y * w1.w + xv.z * w2.w + xv.w * w3.w;
        }
    }

    #pragma unroll
    for (int i = 0; i < NPT; ++i) {
        int n = n0 + tg * NPT + i;
        if (n < N) {
            float d = dinv[n];
            ushort4 o;
            o.x = fbf(acc[i].x * d);
            o.y = fbf(acc[i].y * d);
            o.z = fbf(acc[i].z * d);
            o.w = fbf(acc[i].w * d);
            *(ushort4*)(out + (size_t)n * F + tx * 4) = o;
        }
    }
}

// ======================= gather aggregation (bf16 rows, 8-deep pipeline) =======================
// out[d,:] = bf16( dinv[d] * ( g[d,:] + sum_{s in N(d)} g[s,:] ) ), one wave per node.

__launch_bounds__(256)
__global__ void gather64(const unsigned short* __restrict__ g, const float* __restrict__ dinv,
                         const int* __restrict__ row_ptr, const int* __restrict__ csr_src,
                         unsigned short* __restrict__ out, int N) {
    int gid = blockIdx.x * blockDim.x + threadIdx.x;
    int n = gid >> 6;
    int lane = gid & 63;
    if (n >= N) return;
    int e0 = row_ptr[n], e1 = row_ptr[n + 1];
    float acc = bfu(g[(size_t)n * 64 + lane]);     // self loop
    int e = e0;
    for (; e + 8 <= e1; e += 8) {
        int s[8];
        #pragma unroll
        for (int k = 0; k < 8; ++k) s[k] = csr_src[e + k];
        float v[8];
        #pragma unroll
        for (int k = 0; k < 8; ++k) v[k] = bfu(g[(size_t)s[k] * 64 + lane]);
        acc += ((v[0] + v[1]) + (v[2] + v[3])) + ((v[4] + v[5]) + (v[6] + v[7]));
    }
    if (e < e1) {
        int m = e1 - e;                             // 1..7
        int s[8];
        #pragma unroll
        for (int k = 0; k < 8; ++k) s[k] = csr_src[(e + k < e1) ? e + k : e1 - 1];
        float v[8];
        #pragma unroll
        for (int k = 0; k < 8; ++k) v[k] = bfu(g[(size_t)s[k] * 64 + lane]);
        #pragma unroll
        for (int k = 0; k < 8; ++k) acc += (k < m) ? v[k] : 0.f;  // dup loads hit L1
    }
    out[(size_t)n * 64 + lane] = fbf(dinv[n] * acc);
}

// Layer-3 gather (F=40) with fused bias + log_softmax; fp32 output.
__launch_bounds__(256)
__global__ void gather40_lsm(const unsigned short* __restrict__ g, const float* __restrict__ dinv,
                             const int* __restrict__ row_ptr, const int* __restrict__ csr_src,
                             const float* __restrict__ b3, float* __restrict__ out, int N) {
    int gid = blockIdx.x * blockDim.x + threadIdx.x;
    int n = gid >> 6;
    int lane = gid & 63;
    if (n >= N) return;
    int l = min(lane, NCLASS - 1);                  // lanes 40..63 duplicate lane 39 (no OOB)
    int e0 = row_ptr[n], e1 = row_ptr[n + 1];
    float acc = bfu(g[(size_t)n * NCLASS + l]);
    int e = e0;
    for (; e + 8 <= e1; e += 8) {
        int s[8];
        #pragma unroll
        for (int k = 0; k < 8; ++k) s[k] = csr_src[e + k];
        float v[8];
        #pragma unroll
        for (int k = 0; k < 8; ++k) v[k] = bfu(g[(size_t)s[k] * NCLASS + l]);
        acc += ((v[0] + v[1]) + (v[2] + v[3])) + ((v[4] + v[5]) + (v[6] + v[7]));
    }
    if (e < e1) {
        int m = e1 - e;
        int s[8];
        #pragma unroll
        for (int k = 0; k < 8; ++k) s[k] = csr_src[(e + k < e1) ? e + k : e1 - 1];
        float v[8];
        #pragma unroll
        for (int k = 0; k < 8; ++k) v[k] = bfu(g[(size_t)s[k] * NCLASS + l]);
        #pragma unroll
        for (int k = 0; k < 8; ++k) acc += (k < m) ? v[k] : 0.f;
    }
    float a3 = dinv[n] * acc;
    float v = (lane < NCLASS) ? a3 + b3[lane] : -1e30f;
    float mx = v;
    #pragma unroll
    for (int off = 32; off > 0; off >>= 1)
        mx = fmaxf(mx, __shfl_xor(mx, off, 64));
    float ex = (lane < NCLASS) ? expf(v - mx) : 0.f;
    float sm = ex;
    #pragma unroll
    for (int off = 32; off > 0; off >>= 1)
        sm += __shfl_xor(sm, off, 64);
    if (lane < NCLASS) out[(size_t)n * NCLASS + lane] = v - mx - logf(sm);
}

// ======================= launch =======================

extern "C" void kernel_launch(void* const* d_in, const int* in_sizes, int n_in,
                              void* d_out, int out_size, void* d_ws, size_t ws_size,
                              hipStream_t stream) {
    const float* x  = (const float*)d_in[0];
    const int*   ei = (const int*)  d_in[1];
    const float* W1 = (const float*)d_in[2];
    const float* b1 = (const float*)d_in[3];
    const float* W2 = (const float*)d_in[4];
    const float* b2 = (const float*)d_in[5];
    const float* W3 = (const float*)d_in[6];
    const float* b3 = (const float*)d_in[7];
    const int N = in_sizes[0] / NFEAT;
    const int E = in_sizes[1] / 2;
    const int* src = ei;
    const int* dst = ei + E;
    float* out = (float*)d_out;

    // ---- workspace layout (4-byte units, all sections 256-float aligned) ----
    const size_t Np = ((size_t)N + 256) & ~(size_t)255;    // >= N+1
    const size_t Ep = ((size_t)E + 255) & ~(size_t)255;
    const size_t Fp = (((size_t)N * 32) + 255) & ~(size_t)255;  // N*64 bf16 in floats
    float* base = (float*)d_ws;
    int*   deg     = (int*)(base);                         // Np
    float* dinv    = base + Np;                            // Np
    int*   row_ptr = (int*)(base + 2 * Np);                // Np (uses N+1)
    int*   bsums   = (int*)(base + 3 * Np);                // 256
    int*   bcur    = (int*)(base + 3 * Np + 256);          // 1024
    int2*  ebuf    = (int2*)(base + 3 * Np + 1280);        // 2*Ep floats
    int*   csr_src = (int*)(base + 3 * Np + 1280 + 2 * Ep);// Ep
    unsigned short* tb = (unsigned short*)(base + 3 * Np + 1280 + 3 * Ep);  // Fp floats
    unsigned short* ab = (unsigned short*)(base + 3 * Np + 1280 + 3 * Ep + Fp);
    // total ~ 47 MB

    const int NBLK = (N + 1023) / 1024;
    const int NB = (N + 127) >> 7;                         // 782 buckets of 128 nodes

    // ---- CSR build ----
    hipMemsetAsync(deg, 0, (size_t)N * sizeof(int), stream);
    deg_kernel<<<(E + 255) / 256, 256, 0, stream>>>(dst, deg, E);
    dinv_kernel<<<(N + 255) / 256, 256, 0, stream>>>(deg, dinv, N);
    scan_block_sums<<<NBLK, 256, 0, stream>>>(deg, bsums, N);
    scan_bsums<<<1, 256, 0, stream>>>(bsums, NBLK, row_ptr, N, E);
    scan_final<<<NBLK, 256, 0, stream>>>(deg, bsums, row_ptr, N);
    bcur_init<<<(NB + 255) / 256, 256, 0, stream>>>(row_ptr, bcur, NB);
    bucket_scatter<<<(E + 255) / 256, 256, 0, stream>>>(src, dst, bcur, ebuf, E);
    bucket_to_csr<<<NB, 256, 0, stream>>>(ebuf, row_ptr, csr_src, N);

    const int gatherBlocks = (int)(((size_t)N * 64 + 255) / 256);

    // ---- layer 1 ----
    lin_kernel<NFEAT, NHID, false, false><<<(N + 63) / 64, 256, 0, stream>>>(x, W1, nullptr, dinv, tb, N);
    gather64<<<gatherBlocks, 256, 0, stream>>>(tb, dinv, row_ptr, csr_src, ab, N);

    // ---- layer 2 ----
    lin_kernel<NHID, NHID, true, true><<<(N + 63) / 64, 256, 0, stream>>>(ab, W2, b1, dinv, tb, N);
    gather64<<<gatherBlocks, 256, 0, stream>>>(tb, dinv, row_ptr, csr_src, ab, N);

    // ---- layer 3 ----
    lin_kernel<NHID, NCLASS, true, true><<<(N + 99) / 100, 256, 0, stream>>>(ab, W3, b2, dinv, tb, N);
    gather40_lsm<<<gatherBlocks, 256, 0, stream>>>(tb, dinv, row_ptr, csr_src, b3, out, N);
}

// Round 4
// 375.853 us; speedup vs baseline: 2.0992x; 2.0992x over previous
//
#include <hip/hip_runtime.h>

#define NFEAT 128
#define NHID 64
#define NCLASS 40

#define BSH 8                    // bucket = 256 nodes
#define MAXBIN 512               // supports N <= 131072
#define CH 8192                  // edges per chunk in pass A

// ---------------- bf16 helpers (storage-only precision; compute is fp32) ----------------

__device__ __forceinline__ float bfu(unsigned short u) {
    return __uint_as_float((unsigned)u << 16);
}
__device__ __forceinline__ unsigned short fbf(float f) {
    unsigned u = __float_as_uint(f);
    u += 0x7fffu + ((u >> 16) & 1u);        // round-to-nearest-even
    return (unsigned short)(u >> 16);
}

// ======================= CSR build, hierarchical =======================
// A1: per-chunk LDS histogram -> one global atomic per (chunk,bin).

__launch_bounds__(256)
__global__ void binA1(const int* __restrict__ dst, int* __restrict__ gcount, int E, int nbin) {
    __shared__ int h[MAXBIN];
    const int t = threadIdx.x;
    for (int i = t; i < nbin; i += 256) h[i] = 0;
    __syncthreads();
    const int e0 = blockIdx.x * CH;
    const int e1 = min(e0 + CH, E);
    for (int i = e0 + t; i < e1; i += 256) atomicAdd(&h[dst[i] >> BSH], 1);
    __syncthreads();
    for (int i = t; i < nbin; i += 256) { int c = h[i]; if (c) atomicAdd(&gcount[i], c); }
}

// Tiny scan over bin counts -> bin bases (ebuf AND csr share this layout).
__launch_bounds__(512)
__global__ void binscan(const int* __restrict__ gcount, int* __restrict__ gbase,
                        int* __restrict__ gcur, int* __restrict__ row_ptr,
                        int nbin, int N, int E) {
    __shared__ int sd[512];
    const int t = threadIdx.x;
    int v = (t < nbin) ? gcount[t] : 0;
    sd[t] = v;
    __syncthreads();
    for (int off = 1; off < 512; off <<= 1) {
        int tmp = (t >= off) ? sd[t - off] : 0;
        __syncthreads();
        sd[t] += tmp;
        __syncthreads();
    }
    int excl = sd[t] - v;
    if (t < nbin) { gbase[t] = excl; gcur[t] = excl; }
    if (t == 0) { gbase[nbin] = E; row_ptr[N] = E; }
}

// A2: re-histogram chunk, reserve a contiguous run per bin (1 atomic), scatter
// packed (local_dst<<24 | src) into the run. Runs are wg-private -> full lines.
__launch_bounds__(256)
__global__ void binA2(const int* __restrict__ src, const int* __restrict__ dst,
                      int* __restrict__ gcur, unsigned* __restrict__ ebuf, int E, int nbin) {
    __shared__ int h[MAXBIN];
    __shared__ int base[MAXBIN];
    const int t = threadIdx.x;
    for (int i = t; i < nbin; i += 256) h[i] = 0;
    __syncthreads();
    const int e0 = blockIdx.x * CH;
    const int e1 = min(e0 + CH, E);
    for (int i = e0 + t; i < e1; i += 256) atomicAdd(&h[dst[i] >> BSH], 1);
    __syncthreads();
    for (int i = t; i < nbin; i += 256) {
        int c = h[i];
        if (c) base[i] = atomicAdd(&gcur[i], c);
        h[i] = 0;                               // reuse as local cursor
    }
    __syncthreads();
    for (int i = e0 + t; i < e1; i += 256) {
        int d = dst[i];
        int b = d >> BSH;
        int pos = base[b] + atomicAdd(&h[b], 1);
        ebuf[pos] = ((unsigned)(d & ((1 << BSH) - 1)) << 24) | (unsigned)src[i];
    }
}

// B: one wg per bin. LDS per-node counts -> scan -> row_ptr + dinv + LDS-cursor
// scatter into the bin's private csr_src window. Also replaces deg/dinv kernels.
__launch_bounds__(256)
__global__ void binB(const unsigned* __restrict__ ebuf, const int* __restrict__ gbase,
                     int* __restrict__ row_ptr, float* __restrict__ dinv,
                     int* __restrict__ csr_src, int N) {
    __shared__ int cnt[256];
    __shared__ int sd[256];
    __shared__ int cur[256];
    const int b = blockIdx.x;
    const int n0 = b << BSH;
    const int t = threadIdx.x;
    const int b0 = gbase[b], b1 = gbase[b + 1];
    cnt[t] = 0;
    __syncthreads();
    for (int i = b0 + t; i < b1; i += 256) atomicAdd(&cnt[ebuf[i] >> 24], 1);
    __syncthreads();
    int v = cnt[t];
    sd[t] = v;
    __syncthreads();
    for (int off = 1; off < 256; off <<= 1) {
        int tmp = (t >= off) ? sd[t - off] : 0;
        __syncthreads();
        sd[t] += tmp;
        __syncthreads();
    }
    int excl = sd[t] - v;
    int n = n0 + t;
    if (n < N) {
        row_ptr[n] = b0 + excl;
        dinv[n] = rsqrtf((float)v + 1.0f);      // +1 self loop
    }
    cur[t] = b0 + excl;
    __syncthreads();
    for (int i = b0 + t; i < b1; i += 256) {
        unsigned p = ebuf[i];
        int pos = atomicAdd(&cur[p >> 24], 1);
        csr_src[pos] = (int)(p & 0xffffffu);
    }
}

// ======================= dense linear =======================
// out[n,:] = bf16( dinv[n] * (f(in[n,:]) @ W) ), f = relu(x + bias_prev) if RELU_BIAS.

template<int K, int F, bool RELU_BIAS, bool IN_BF16>
__launch_bounds__(256)
__global__ void lin_kernel(const void* __restrict__ in_, const float* __restrict__ W,
                           const float* __restrict__ bias, const float* __restrict__ dinv,
                           unsigned short* __restrict__ out, int N) {
    constexpr int FT = F / 4;
    constexpr int TG = 256 / FT;
    constexpr int NPT = 4;
    constexpr int NODES = TG * NPT;
    constexpr int KP = K + 4;

    __shared__ alignas(16) float Ws[K * F];
    __shared__ alignas(16) float xs[NODES * KP];

    const int tid = threadIdx.x;
    const int n0 = blockIdx.x * NODES;

    for (int q = tid; q < K * F / 4; q += 256)
        ((float4*)Ws)[q] = ((const float4*)W)[q];

    if constexpr (IN_BF16) {
        const unsigned short* in = (const unsigned short*)in_;
        for (int q = tid; q < NODES * (K / 8); q += 256) {
            int ni = q / (K / 8);
            int c = q - ni * (K / 8);
            int n = n0 + ni;
            float v[8];
            if (n < N) {
                uint4 raw = *(const uint4*)(in + (size_t)n * K + c * 8);
                unsigned rr[4] = {raw.x, raw.y, raw.z, raw.w};
                #pragma unroll
                for (int j = 0; j < 4; ++j) {
                    v[2 * j]     = __uint_as_float(rr[j] << 16);
                    v[2 * j + 1] = __uint_as_float(rr[j] & 0xffff0000u);
                }
            } else {
                #pragma unroll
                for (int j = 0; j < 8; ++j) v[j] = 0.f;
            }
            if constexpr (RELU_BIAS) {
                #pragma unroll
                for (int j = 0; j < 8; ++j) v[j] = fmaxf(v[j] + bias[c * 8 + j], 0.f);
            }
            *(float4*)&xs[ni * KP + c * 8]     = make_float4(v[0], v[1], v[2], v[3]);
            *(float4*)&xs[ni * KP + c * 8 + 4] = make_float4(v[4], v[5], v[6], v[7]);
        }
    } else {
        const float* in = (const float*)in_;
        for (int q = tid; q < NODES * (K / 4); q += 256) {
            int ni = q / (K / 4);
            int kq = q - ni * (K / 4);
            int n = n0 + ni;
            float4 v = make_float4(0.f, 0.f, 0.f, 0.f);
            if (n < N) v = ((const float4*)in)[(size_t)n * (K / 4) + kq];
            if constexpr (RELU_BIAS) {
                float4 b = ((const float4*)bias)[kq];
                v.x = fmaxf(v.x + b.x, 0.f);
                v.y = fmaxf(v.y + b.y, 0.f);
                v.z = fmaxf(v.z + b.z, 0.f);
                v.w = fmaxf(v.w + b.w, 0.f);
            }
            *(float4*)&xs[ni * KP + kq * 4] = v;
        }
    }
    __syncthreads();

    const int tx = tid % FT;
    const int tg = tid / FT;
    if (tg >= TG) return;

    float4 acc[NPT];
    #pragma unroll
    for (int i = 0; i < NPT; ++i) acc[i] = make_float4(0.f, 0.f, 0.f, 0.f);

    #pragma unroll 4
    for (int kq = 0; kq < K / 4; ++kq) {
        float4 w0 = *(const float4*)&Ws[(kq * 4 + 0) * F + tx * 4];
        float4 w1 = *(const float4*)&Ws[(kq * 4 + 1) * F + tx * 4];
        float4 w2 = *(const float4*)&Ws[(kq * 4 + 2) * F + tx * 4];
        float4 w3 = *(const float4*)&Ws[(kq * 4 + 3) * F + tx * 4];
        #pragma unroll
        for (int i = 0; i < NPT; ++i) {
            float4 xv = *(const float4*)&xs[(tg * NPT + i) * KP + kq * 4];
            acc[i].x += xv.x * w0.x + xv.y * w1.x + xv.z * w2.x + xv.w * w3.x;
            acc[i].y += xv.x * w0.y + xv.y * w1.y + xv.z * w2.y + xv.w * w3.y;
            acc[i].z += xv.x * w0.z + xv.y * w1.z + xv.z * w2.z + xv.w * w3.z;
            acc[i].w += xv.x * w0.w + xv.y * w1.w + xv.z * w2.w + xv.w * w3.w;
        }
    }

    #pragma unroll
    for (int i = 0; i < NPT; ++i) {
        int n = n0 + tg * NPT + i;
        if (n < N) {
            float d = dinv[n];
            ushort4 o;
            o.x = fbf(acc[i].x * d);
            o.y = fbf(acc[i].y * d);
            o.z = fbf(acc[i].z * d);
            o.w = fbf(acc[i].w * d);
            *(ushort4*)(out + (size_t)n * F + tx * 4) = o;
        }
    }
}

// ======================= gather aggregation (bf16 rows, 8-deep pipeline) =======================

__launch_bounds__(256)
__global__ void gather64(const unsigned short* __restrict__ g, const float* __restrict__ dinv,
                         const int* __restrict__ row_ptr, const int* __restrict__ csr_src,
                         unsigned short* __restrict__ out, int N) {
    int gid = blockIdx.x * blockDim.x + threadIdx.x;
    int n = gid >> 6;
    int lane = gid & 63;
    if (n >= N) return;
    int e0 = row_ptr[n], e1 = row_ptr[n + 1];
    float acc = bfu(g[(size_t)n * 64 + lane]);     // self loop
    int e = e0;
    for (; e + 8 <= e1; e += 8) {
        int s[8];
        #pragma unroll
        for (int k = 0; k < 8; ++k) s[k] = csr_src[e + k];
        float v[8];
        #pragma unroll
        for (int k = 0; k < 8; ++k) v[k] = bfu(g[(size_t)s[k] * 64 + lane]);
        acc += ((v[0] + v[1]) + (v[2] + v[3])) + ((v[4] + v[5]) + (v[6] + v[7]));
    }
    if (e < e1) {
        int m = e1 - e;
        int s[8];
        #pragma unroll
        for (int k = 0; k < 8; ++k) s[k] = csr_src[(e + k < e1) ? e + k : e1 - 1];
        float v[8];
        #pragma unroll
        for (int k = 0; k < 8; ++k) v[k] = bfu(g[(size_t)s[k] * 64 + lane]);
        #pragma unroll
        for (int k = 0; k < 8; ++k) acc += (k < m) ? v[k] : 0.f;
    }
    out[(size_t)n * 64 + lane] = fbf(dinv[n] * acc);
}

__launch_bounds__(256)
__global__ void gather40_lsm(const unsigned short* __restrict__ g, const float* __restrict__ dinv,
                             const int* __restrict__ row_ptr, const int* __restrict__ csr_src,
                             const float* __restrict__ b3, float* __restrict__ out, int N) {
    int gid = blockIdx.x * blockDim.x + threadIdx.x;
    int n = gid >> 6;
    int lane = gid & 63;
    if (n >= N) return;
    int l = min(lane, NCLASS - 1);
    int e0 = row_ptr[n], e1 = row_ptr[n + 1];
    float acc = bfu(g[(size_t)n * NCLASS + l]);
    int e = e0;
    for (; e + 8 <= e1; e += 8) {
        int s[8];
        #pragma unroll
        for (int k = 0; k < 8; ++k) s[k] = csr_src[e + k];
        float v[8];
        #pragma unroll
        for (int k = 0; k < 8; ++k) v[k] = bfu(g[(size_t)s[k] * NCLASS + l]);
        acc += ((v[0] + v[1]) + (v[2] + v[3])) + ((v[4] + v[5]) + (v[6] + v[7]));
    }
    if (e < e1) {
        int m = e1 - e;
        int s[8];
        #pragma unroll
        for (int k = 0; k < 8; ++k) s[k] = csr_src[(e + k < e1) ? e + k : e1 - 1];
        float v[8];
        #pragma unroll
        for (int k = 0; k < 8; ++k) v[k] = bfu(g[(size_t)s[k] * NCLASS + l]);
        #pragma unroll
        for (int k = 0; k < 8; ++k) acc += (k < m) ? v[k] : 0.f;
    }
    float a3 = dinv[n] * acc;
    float v = (lane < NCLASS) ? a3 + b3[lane] : -1e30f;
    float mx = v;
    #pragma unroll
    for (int off = 32; off > 0; off >>= 1)
        mx = fmaxf(mx, __shfl_xor(mx, off, 64));
    float ex = (lane < NCLASS) ? expf(v - mx) : 0.f;
    float sm = ex;
    #pragma unroll
    for (int off = 32; off > 0; off >>= 1)
        sm += __shfl_xor(sm, off, 64);
    if (lane < NCLASS) out[(size_t)n * NCLASS + lane] = v - mx - logf(sm);
}

// ======================= launch =======================

extern "C" void kernel_launch(void* const* d_in, const int* in_sizes, int n_in,
                              void* d_out, int out_size, void* d_ws, size_t ws_size,
                              hipStream_t stream) {
    const float* x  = (const float*)d_in[0];
    const int*   ei = (const int*)  d_in[1];
    const float* W1 = (const float*)d_in[2];
    const float* b1 = (const float*)d_in[3];
    const float* W2 = (const float*)d_in[4];
    const float* b2 = (const float*)d_in[5];
    const float* W3 = (const float*)d_in[6];
    const float* b3 = (const float*)d_in[7];
    const int N = in_sizes[0] / NFEAT;
    const int E = in_sizes[1] / 2;
    const int* src = ei;
    const int* dst = ei + E;
    float* out = (float*)d_out;

    const int nbin = (N + (1 << BSH) - 1) >> BSH;          // 391 for N=100000

    // ---- workspace layout (4-byte units, 256-aligned sections) ----
    const size_t Np = ((size_t)N + 256) & ~(size_t)255;
    const size_t Ep = ((size_t)E + 255) & ~(size_t)255;
    const size_t Fp = (((size_t)N * 32) + 255) & ~(size_t)255;
    float* base = (float*)d_ws;
    int*      gcount  = (int*)(base);                       // MAXBIN
    int*      gbase   = (int*)(base + MAXBIN);              // MAXBIN+1 (padded)
    int*      gcur    = (int*)(base + 2 * MAXBIN + 256);    // MAXBIN
    int*      row_ptr = (int*)(base + 3 * MAXBIN + 256);    // Np
    float*    dinv    =        base + 3 * MAXBIN + 256 + Np;
    unsigned* ebuf    = (unsigned*)(base + 3 * MAXBIN + 256 + 2 * Np);
    int*      csr_src = (int*)(base + 3 * MAXBIN + 256 + 2 * Np + Ep);
    unsigned short* tb = (unsigned short*)(base + 3 * MAXBIN + 256 + 2 * Np + 2 * Ep);
    unsigned short* ab = (unsigned short*)(base + 3 * MAXBIN + 256 + 2 * Np + 2 * Ep + Fp);
    // total ~ 39 MB

    const int nchunk = (E + CH - 1) / CH;                   // 196

    // ---- CSR build (also produces dinv) ----
    hipMemsetAsync(gcount, 0, MAXBIN * sizeof(int), stream);
    binA1<<<nchunk, 256, 0, stream>>>(dst, gcount, E, nbin);
    binscan<<<1, 512, 0, stream>>>(gcount, gbase, gcur, row_ptr, nbin, N, E);
    binA2<<<nchunk, 256, 0, stream>>>(src, dst, gcur, ebuf, E, nbin);
    binB<<<nbin, 256, 0, stream>>>(ebuf, gbase, row_ptr, dinv, csr_src, N);

    const int gatherBlocks = (int)(((size_t)N * 64 + 255) / 256);

    // ---- layer 1 ----
    lin_kernel<NFEAT, NHID, false, false><<<(N + 63) / 64, 256, 0, stream>>>(x, W1, nullptr, dinv, tb, N);
    gather64<<<gatherBlocks, 256, 0, stream>>>(tb, dinv, row_ptr, csr_src, ab, N);

    // ---- layer 2 ----
    lin_kernel<NHID, NHID, true, true><<<(N + 63) / 64, 256, 0, stream>>>(ab, W2, b1, dinv, tb, N);
    gather64<<<gatherBlocks, 256, 0, stream>>>(tb, dinv, row_ptr, csr_src, ab, N);

    // ---- layer 3 ----
    lin_kernel<NHID, NCLASS, true, true><<<(N + 99) / 100, 256, 0, stream>>>(ab, W3, b2, dinv, tb, N);
    gather40_lsm<<<gatherBlocks, 256, 0, stream>>>(tb, dinv, row_ptr, csr_src, b3, out, N);
}